// Round 10
// baseline (390.071 us; speedup 1.0000x reference)
//
#include <hip/hip_runtime.h>
#include <hip/hip_bf16.h>
#include <hip/hip_fp16.h>
#include <stdint.h>

#define N_SRC0 400000
#define N_DST0 100000
#define N_DST1 25000

// coarse-bucket geometry (node counts are fixed)
#define SH_D0 9
#define NK_D0 196      // ceil(100000/512)
#define SH_S0 9
#define NK_S0 782      // ceil(400000/512)
#define SH_D1 8
#define NK_D1 98       // ceil(25000/256)
#define SH_S1 9
#define NK_S1 196      // ceil(100000/512)
#define NB0 512
#define NB1 128

// bh concatenated layout offsets (element indices; scan order == staging order)
#define BH_D0 0
#define BH_S0 (NK_D0 * NB0)                    // 100352
#define BH_D1 (BH_S0 + NK_S0 * NB0)            // 500736
#define BH_S1 (BH_D1 + NK_D1 * NB1)            // 513280
#define BH_TOT (BH_S1 + NK_S1 * NB1)           // 538368

typedef __attribute__((ext_vector_type(8))) short short8;
typedef __attribute__((ext_vector_type(4))) float f32x4;

__device__ __forceinline__ unsigned short f2bf(float f) {
    __hip_bfloat16 h = __float2bfloat16(f);
    union { __hip_bfloat16 h; unsigned short u; } c;
    c.h = h;
    return c.u;
}
__device__ __forceinline__ uint32_t packbf2(float a, float b) {
    return (uint32_t)f2bf(a) | ((uint32_t)f2bf(b) << 16);
}
__device__ __forceinline__ __half2 u2h2(uint32_t u) {
    return __builtin_bit_cast(__half2, u);
}

// ============ pass 1: per-block coarse histograms (src & dst fused) ============
__device__ __forceinline__ void hist_body(
        const int* __restrict__ src, const int* __restrict__ dst, int n,
        int sshift, int snb, int dshift, int dnb, int NB, int blk,
        int* __restrict__ bhd, int* __restrict__ bhs, int* h) {
    for (int i = threadIdx.x; i < dnb + snb; i += 256) h[i] = 0;
    __syncthreads();
    const int per = (n + NB - 1) / NB;
    const int b = blk * per;
    const int e = min(b + per, n);
    for (int i = b + threadIdx.x; i < e; i += 256) {
        atomicAdd(&h[dst[i] >> dshift], 1);
        atomicAdd(&h[dnb + (src[i] >> sshift)], 1);
    }
    __syncthreads();
    for (int i = threadIdx.x; i < dnb; i += 256) bhd[(size_t)i * NB + blk] = h[i];
    for (int i = threadIdx.x; i < snb; i += 256) bhs[(size_t)i * NB + blk] = h[dnb + i];
}

__global__ __launch_bounds__(256) void hist_fused(
        const int* __restrict__ src0, const int* __restrict__ dst0, int E0,
        const int* __restrict__ src1, const int* __restrict__ dst1, int E1,
        int* __restrict__ bh) {
    extern __shared__ int h[];
    if (blockIdx.x < NB0)
        hist_body(src0, dst0, E0, SH_S0, NK_S0, SH_D0, NK_D0, NB0, blockIdx.x,
                  bh + BH_D0, bh + BH_S0, h);
    else
        hist_body(src1, dst1, E1, SH_S1, NK_S1, SH_D1, NK_D1, NB1, blockIdx.x - NB0,
                  bh + BH_D1, bh + BH_S1, h);
}

// ============ global exclusive scan over bh (block-local; sums folded later) ====
#define SCAN_ITEMS 8
#define SCAN_TILE 2048   // == 256 * SCAN_ITEMS; sums index = elem >> 11

__global__ __launch_bounds__(256) void scan1_kernel(
        const int* __restrict__ in, int* __restrict__ out,
        int* __restrict__ sums, int n) {
    __shared__ int lds[256];
    const int tid = threadIdx.x;
    const int base = blockIdx.x * SCAN_TILE + tid * SCAN_ITEMS;
    int v[SCAN_ITEMS];
    int run = 0;
    #pragma unroll
    for (int i = 0; i < SCAN_ITEMS; ++i) {
        int t = (base + i < n) ? in[base + i] : 0;
        v[i] = run;
        run += t;
    }
    lds[tid] = run;
    __syncthreads();
    int incl = run;
    for (int off = 1; off < 256; off <<= 1) {
        int u = (tid >= off) ? lds[tid - off] : 0;
        __syncthreads();
        incl += u;
        lds[tid] = incl;
        __syncthreads();
    }
    if (tid == 255) sums[blockIdx.x] = incl;
    int excl = incl - run;
    #pragma unroll
    for (int i = 0; i < SCAN_ITEMS; ++i)
        if (base + i < n) out[base + i] = excl + v[i];
}

__global__ __launch_bounds__(256) void scan2_kernel(int* __restrict__ sums, int nb) {
    __shared__ int lds[256];
    const int tid = threadIdx.x;
    const int base = tid * 4;
    int v[4];
    int run = 0;
    #pragma unroll
    for (int i = 0; i < 4; ++i) {
        int t = (base + i < nb) ? sums[base + i] : 0;
        v[i] = run;
        run += t;
    }
    lds[tid] = run;
    __syncthreads();
    int incl = run;
    for (int off = 1; off < 256; off <<= 1) {
        int u = (tid >= off) ? lds[tid - off] : 0;
        __syncthreads();
        incl += u;
        lds[tid] = incl;
        __syncthreads();
    }
    int excl = incl - run;
    #pragma unroll
    for (int i = 0; i < 4; ++i)
        if (base + i < nb) sums[base + i] = excl + v[i];
}

// ============ pass 2: scatter to bucket-major staging ============
// dst-keyed table (u32): (d_local << ksh) | s ; src-keyed table (u16): s & smask.
// cursors = bh[..] + sums[gidx>>11] - Ttable  (table-relative)
__device__ __forceinline__ void scat_body(
        const int* __restrict__ src, const int* __restrict__ dst, int n,
        int sshift, int snb, int dshift, int dnb, int NB, int blk, int ksh,
        const int* __restrict__ bhd, const int* __restrict__ bhs,
        const int* __restrict__ sums, int goffd, int goffs, int Td, int Ts,
        uint32_t* __restrict__ stg_d, unsigned short* __restrict__ stg_s, int* cur) {
    for (int i = threadIdx.x; i < dnb; i += 256) {
        int gi = goffd + i * NB + blk;
        cur[i] = bhd[(size_t)i * NB + blk] + sums[gi >> 11] - Td;
    }
    for (int i = threadIdx.x; i < snb; i += 256) {
        int gi = goffs + i * NB + blk;
        cur[dnb + i] = bhs[(size_t)i * NB + blk] + sums[gi >> 11] - Ts;
    }
    __syncthreads();
    const int per = (n + NB - 1) / NB;
    const int b = blk * per;
    const int e = min(b + per, n);
    const int dmask = (1 << dshift) - 1;
    const int smask = (1 << sshift) - 1;
    for (int i = b + threadIdx.x; i < e; i += 256) {
        int s = src[i], d = dst[i];
        int pd = atomicAdd(&cur[d >> dshift], 1);
        stg_d[pd] = ((uint32_t)(d & dmask) << ksh) | (uint32_t)s;
        int ps = atomicAdd(&cur[dnb + (s >> sshift)], 1);
        stg_s[ps] = (unsigned short)(s & smask);
    }
}

__global__ __launch_bounds__(256) void scat_fused(
        const int* __restrict__ src0, const int* __restrict__ dst0, int E0,
        const int* __restrict__ src1, const int* __restrict__ dst1, int E1,
        const int* __restrict__ bh, const int* __restrict__ sums,
        uint32_t* __restrict__ stgd0, unsigned short* __restrict__ stgs0,
        uint32_t* __restrict__ stgd1, unsigned short* __restrict__ stgs1) {
    extern __shared__ int cur[];
    if (blockIdx.x < NB0)
        scat_body(src0, dst0, E0, SH_S0, NK_S0, SH_D0, NK_D0, NB0, blockIdx.x, 19,
                  bh + BH_D0, bh + BH_S0, sums, BH_D0, BH_S0, 0, E0,
                  stgd0, stgs0, cur);
    else
        scat_body(src1, dst1, E1, SH_S1, NK_S1, SH_D1, NK_D1, NB1, blockIdx.x - NB0, 17,
                  bh + BH_D1, bh + BH_S1, sums, BH_D1, BH_S1, 2 * E0, 2 * E0 + E1,
                  stgd1, stgs1, cur);
}

// ============ pass 3: per-bucket fine CSR / degree / prescale / packw (fused) ====
// bases are table-relative: base = bh[k*NB] + sums[(goff+k*NB)>>11] - T
__device__ __forceinline__ int fold_base(const int* bht, const int* sums,
                                         int goff, int NB, int T, int k) {
    int gi = goff + k * NB;
    return bht[(size_t)k * NB] + sums[gi >> 11] - T;
}

__device__ __forceinline__ void fine_csr_body(
        const uint32_t* __restrict__ stg, const int* __restrict__ bht,
        const int* __restrict__ sums, int goff, int T,
        int NB, int shift, int ksh, int nbins, int total, int nbkt, int k,
        int* __restrict__ off, int* __restrict__ esrc, int* fine, int* part) {
    const int fb = 1 << shift;
    const int base = fold_base(bht, sums, goff, NB, T, k);
    const int end = (k + 1 < nbkt) ? fold_base(bht, sums, goff, NB, T, k + 1) : total;
    const int gb = k << shift;
    const int t = threadIdx.x;
    const uint32_t mask = (1u << ksh) - 1;
    for (int i = t; i < fb; i += 256) fine[i] = 0;
    __syncthreads();
    for (int i = base + t; i < end; i += 256)
        atomicAdd(&fine[stg[i] >> ksh], 1);
    __syncthreads();
    int a0 = (2 * t < fb) ? fine[2 * t] : 0;
    int a1 = (2 * t + 1 < fb) ? fine[2 * t + 1] : 0;
    part[t] = a0 + a1;
    __syncthreads();
    int incl = part[t];
    for (int o = 1; o < 256; o <<= 1) {
        int u = (t >= o) ? part[t - o] : 0;
        __syncthreads();
        incl += u;
        part[t] = incl;
        __syncthreads();
    }
    int excl = incl - (a0 + a1);
    if (2 * t < fb) fine[2 * t] = excl;
    if (2 * t + 1 < fb) fine[2 * t + 1] = excl + a0;
    __syncthreads();
    for (int i = t; i < fb; i += 256) {
        int g = gb + i;
        if (g < nbins) off[g] = base + fine[i];
    }
    if (k == nbkt - 1 && t == 0) off[nbins] = total;
    __syncthreads();
    for (int i = base + t; i < end; i += 256) {
        uint32_t v = stg[i];
        int p = atomicAdd(&fine[v >> ksh], 1);
        esrc[base + p] = (int)(v & mask);
    }
}

// src0 degree + fused prescale: xs[row] = f16(x[row] * rsqrt(deg(row)))
__device__ __forceinline__ void fine_deg_pre_body(
        const unsigned short* __restrict__ stg, const int* __restrict__ bht,
        const int* __restrict__ sums, int goff, int T,
        int NB, int shift, int nbins, int total, int nbkt, int k,
        const float4* __restrict__ x4, uint2* __restrict__ xs, int* fine) {
    const int fb = 1 << shift;
    const int base = fold_base(bht, sums, goff, NB, T, k);
    const int end = (k + 1 < nbkt) ? fold_base(bht, sums, goff, NB, T, k + 1) : total;
    const int gb = k << shift;
    for (int i = threadIdx.x; i < fb; i += 256) fine[i] = 0;
    __syncthreads();
    for (int i = base + threadIdx.x; i < end; i += 256)
        atomicAdd(&fine[stg[i]], 1);
    __syncthreads();
    // counts -> cs (bitcast float, in place)
    for (int i = threadIdx.x; i < fb; i += 256) {
        int c = fine[i];
        float r = c > 0 ? rsqrtf((float)c) : 0.f;
        fine[i] = __float_as_int(r);
    }
    __syncthreads();
    // prescale this bucket's rows: 32 float4 per row, coalesced
    const int nrow = min(fb, nbins - gb);
    for (int j = threadIdx.x; j < nrow * 32; j += 256) {
        int r = j >> 5;
        float cs = __int_as_float(fine[r]);
        size_t idx = (size_t)(gb + r) * 32 + (j & 31);
        float4 v = x4[idx];
        uint2 o;
        o.x = __builtin_bit_cast(uint32_t, __floats2half2_rn(v.x * cs, v.y * cs));
        o.y = __builtin_bit_cast(uint32_t, __floats2half2_rn(v.z * cs, v.w * cs));
        xs[idx] = o;
    }
}

__device__ __forceinline__ void fine_deg_body(
        const unsigned short* __restrict__ stg, const int* __restrict__ bht,
        const int* __restrict__ sums, int goff, int T,
        int NB, int shift, int nbins, int total, int nbkt, int k,
        float* __restrict__ csf, int* fine) {
    const int fb = 1 << shift;
    const int base = fold_base(bht, sums, goff, NB, T, k);
    const int end = (k + 1 < nbkt) ? fold_base(bht, sums, goff, NB, T, k + 1) : total;
    const int gb = k << shift;
    for (int i = threadIdx.x; i < fb; i += 256) fine[i] = 0;
    __syncthreads();
    for (int i = base + threadIdx.x; i < end; i += 256)
        atomicAdd(&fine[stg[i]], 1);
    __syncthreads();
    for (int i = threadIdx.x; i < fb; i += 256) {
        int g = gb + i;
        if (g < nbins) {
            int c = fine[i];
            csf[g] = c > 0 ? rsqrtf((float)c) : 0.f;
        }
    }
}

__global__ __launch_bounds__(256) void fine_fused(
        const uint32_t* __restrict__ stgd0, const unsigned short* __restrict__ stgs0,
        const uint32_t* __restrict__ stgd1, const unsigned short* __restrict__ stgs1,
        const int* __restrict__ bh, const int* __restrict__ sums,
        int E0, int E1,
        int* __restrict__ off0, int* __restrict__ esrc0,
        int* __restrict__ off1, int* __restrict__ esrc1,
        const float4* __restrict__ x4, uint2* __restrict__ xs,
        float* __restrict__ cs1,
        const float* __restrict__ W0, const float* __restrict__ W1,
        unsigned short* __restrict__ W0p, unsigned short* __restrict__ W1p) {
    __shared__ int fine[512];
    __shared__ int part[256];
    int kb = blockIdx.x;
    if (kb < NK_D0) {
        fine_csr_body(stgd0, bh + BH_D0, sums, BH_D0, 0,
                      NB0, SH_D0, 19, N_DST0, E0, NK_D0, kb, off0, esrc0, fine, part);
        return;
    }
    kb -= NK_D0;
    if (kb < NK_S0) {
        fine_deg_pre_body(stgs0, bh + BH_S0, sums, BH_S0, E0,
                          NB0, SH_S0, N_SRC0, E0, NK_S0, kb, x4, xs, fine);
        return;
    }
    kb -= NK_S0;
    if (kb < NK_D1) {
        fine_csr_body(stgd1, bh + BH_D1, sums, BH_D1, 2 * E0,
                      NB1, SH_D1, 17, N_DST1, E1, NK_D1, kb, off1, esrc1, fine, part);
        return;
    }
    kb -= NK_D1;
    if (kb < NK_S1) {
        fine_deg_body(stgs1, bh + BH_S1, sums, BH_S1, 2 * E0 + E1,
                      NB1, SH_S1, N_DST0, E1, NK_S1, kb, cs1, fine);
        return;
    }
    kb -= NK_S1;
    // weight packs (independent of sort data)
    if (kb < 128) {
        int id = kb * 256 + threadIdx.x;
        int kk = id & 31, n2 = (id >> 5) & 255, kt = id >> 13;
        W0p[id] = f2bf(W0[(kt * 32 + kk) * 256 + n2]);
    } else {
        int id = (kb - 128) * 256 + threadIdx.x;
        int kk = id & 31, n2 = (id >> 5) & 63, kt = id >> 11;
        W1p[id] = f2bf(W1[(kt * 32 + kk) * 64 + n2]);
    }
}

// ---------------- layer-0 aggregation: 64 lanes/row, u32 f16 gather, pk_add ----
__global__ __launch_bounds__(256) void agg0_kernel(
        const uint32_t* __restrict__ xs, const int* __restrict__ esrc,
        const int* __restrict__ off, uint32_t* __restrict__ aggb) {
    const int row = blockIdx.x * 4 + (threadIdx.x >> 6);
    const uint32_t t = threadIdx.x & 63;
    const int b = off[row], e = off[row + 1];
    const __half2 z = __builtin_bit_cast(__half2, 0u);
    __half2 a[16];
    #pragma unroll
    for (int k = 0; k < 16; ++k) a[k] = z;
    int i = b;
    for (; i + 15 < e; i += 16) {
        uint32_t idx[16];
        #pragma unroll
        for (int k = 0; k < 16; ++k)
            idx[k] = ((uint32_t)esrc[i + k] << 6) + t;
        #pragma unroll
        for (int k = 0; k < 16; ++k)
            a[k] = __hadd2(a[k], u2h2(xs[idx[k]]));
    }
    for (; i + 3 < e; i += 4) {
        #pragma unroll
        for (int k = 0; k < 4; ++k)
            a[k] = __hadd2(a[k], u2h2(xs[((uint32_t)esrc[i + k] << 6) + t]));
    }
    for (; i < e; ++i)
        a[0] = __hadd2(a[0], u2h2(xs[((uint32_t)esrc[i] << 6) + t]));
    #pragma unroll
    for (int k = 0; k < 8; ++k) a[k] = __hadd2(a[k], a[k + 8]);
    #pragma unroll
    for (int k = 0; k < 4; ++k) a[k] = __hadd2(a[k], a[k + 4]);
    __half2 s = __hadd2(__hadd2(a[0], a[1]), __hadd2(a[2], a[3]));
    float cd = (e > b) ? rsqrtf((float)(e - b)) : 0.f;
    aggb[(size_t)row * 64 + t] = packbf2(__low2float(s) * cd, __high2float(s) * cd);
}

// ---------------- fused GEMM: h = relu(agg@W0+b0) in LDS; y = (h@W1)*cs1 ----
__global__ __launch_bounds__(256) void gemm01_mfma(
        const short* __restrict__ A,            // aggb [N_DST0][128] bf16
        const short* __restrict__ B0p,          // [4][256][32] bf16
        const float* __restrict__ bias0,        // [256]
        const short* __restrict__ B1p,          // [8][64][32] bf16
        const float* __restrict__ cs1,          // [N_DST0]
        __half* __restrict__ Y) {               // [N_DST0][64] f16
    __shared__ short hs[32][264];               // row stride 528B: 2-way bank alias (free)
    const int w = threadIdx.x >> 6;
    const int l = threadIdx.x & 63;
    const int rbase = blockIdx.x * 32;
    const int lr = l & 15;
    const int lk = (l >> 4) * 8;
    const int orow0 = (l >> 4) * 4;

    // ---- phase A: h tile ----
    {
        const int cbase = w * 64;
        f32x4 acc[2][4] = {};
        #pragma unroll
        for (int kt = 0; kt < 4; ++kt) {
            short8 a[2], b[4];
            #pragma unroll
            for (int rt = 0; rt < 2; ++rt)
                a[rt] = *(const short8*)(A + (size_t)(rbase + rt * 16 + lr) * 128 + kt * 32 + lk);
            #pragma unroll
            for (int ct = 0; ct < 4; ++ct)
                b[ct] = *(const short8*)(B0p + (size_t)(kt * 256 + cbase + ct * 16 + lr) * 32 + lk);
            #pragma unroll
            for (int rt = 0; rt < 2; ++rt)
                #pragma unroll
                for (int ct = 0; ct < 4; ++ct)
                    acc[rt][ct] = __builtin_amdgcn_mfma_f32_16x16x32_bf16(a[rt], b[ct], acc[rt][ct], 0, 0, 0);
        }
        #pragma unroll
        for (int rt = 0; rt < 2; ++rt) {
            #pragma unroll
            for (int ct = 0; ct < 4; ++ct) {
                int col = cbase + ct * 16 + lr;
                float bv = bias0[col];
                #pragma unroll
                for (int j = 0; j < 4; ++j)
                    hs[rt * 16 + orow0 + j][col] = (short)f2bf(fmaxf(acc[rt][ct][j] + bv, 0.f));
            }
        }
    }
    __syncthreads();

    // ---- phase B: y tile, wave w covers cols [w*16, w*16+16), K = 256 ----
    {
        f32x4 acc2[2] = {};
        #pragma unroll
        for (int kt = 0; kt < 8; ++kt) {
            short8 b1 = *(const short8*)(B1p + (size_t)(kt * 64 + w * 16 + lr) * 32 + lk);
            #pragma unroll
            for (int rt = 0; rt < 2; ++rt) {
                short8 av = *(const short8*)(&hs[rt * 16 + lr][kt * 32 + lk]);
                acc2[rt] = __builtin_amdgcn_mfma_f32_16x16x32_bf16(av, b1, acc2[rt], 0, 0, 0);
            }
        }
        #pragma unroll
        for (int rt = 0; rt < 2; ++rt) {
            #pragma unroll
            for (int j = 0; j < 4; ++j) {
                int row = rbase + rt * 16 + orow0 + j;
                float c = cs1[row];
                Y[(size_t)row * 64 + w * 16 + lr] = __float2half(acc2[rt][j] * c);
            }
        }
    }
}

// ---------------- layer-1 aggregation: 16 lanes/row, uint2 f16 gather ------
__global__ __launch_bounds__(256) void agg1_kernel(
        const uint2* __restrict__ y2, const int* __restrict__ esrc,
        const int* __restrict__ off, const float* __restrict__ bias,
        float* __restrict__ out, int nrows) {
    int row = blockIdx.x * 16 + (threadIdx.x >> 4);
    int t = threadIdx.x & 15;
    if (row >= nrows) return;
    int b = off[row], e = off[row + 1];
    const __half2 z = __builtin_bit_cast(__half2, 0u);
    __half2 aA0 = z, aA1 = z, aB0 = z, aB1 = z;
    int i = b;
    for (; i + 8 <= e; i += 8) {
        #pragma unroll
        for (int k = 0; k < 8; k += 2) {
            int s0 = esrc[i + k], s1 = esrc[i + k + 1];
            uint2 v0 = y2[(size_t)s0 * 16 + t];
            uint2 v1 = y2[(size_t)s1 * 16 + t];
            aA0 = __hadd2(aA0, u2h2(v0.x));
            aA1 = __hadd2(aA1, u2h2(v0.y));
            aB0 = __hadd2(aB0, u2h2(v1.x));
            aB1 = __hadd2(aB1, u2h2(v1.y));
        }
    }
    for (; i < e; ++i) {
        uint2 v = y2[(size_t)esrc[i] * 16 + t];
        aA0 = __hadd2(aA0, u2h2(v.x));
        aA1 = __hadd2(aA1, u2h2(v.y));
    }
    float cd = (e > b) ? rsqrtf((float)(e - b)) : 0.f;
    __half2 s0 = __hadd2(aA0, aB0), s1 = __hadd2(aA1, aB1);
    float4 bv = *(const float4*)(bias + t * 4);
    float4 o;
    o.x = fmaxf(__low2float(s0) * cd + bv.x, 0.f);
    o.y = fmaxf(__high2float(s0) * cd + bv.y, 0.f);
    o.z = fmaxf(__low2float(s1) * cd + bv.z, 0.f);
    o.w = fmaxf(__high2float(s1) * cd + bv.w, 0.f);
    *(float4*)(out + (size_t)row * 64 + t * 4) = o;
}

extern "C" void kernel_launch(void* const* d_in, const int* in_sizes, int n_in,
                              void* d_out, int out_size, void* d_ws, size_t ws_size,
                              hipStream_t stream) {
    const float* x    = (const float*)d_in[0];
    const int*   src0 = (const int*)d_in[1];
    const int*   dst0 = (const int*)d_in[2];
    const int*   src1 = (const int*)d_in[3];
    const int*   dst1 = (const int*)d_in[4];
    const float* W0   = (const float*)d_in[5];
    const float* b0   = (const float*)d_in[6];
    const float* W1   = (const float*)d_in[7];
    const float* b1   = (const float*)d_in[8];
    float* out = (float*)d_out;

    const int E0 = in_sizes[1];
    const int E1 = in_sizes[3];

    char* p = (char*)d_ws;
    auto alloc = [&](size_t bytes) {
        char* r = p;
        p += (bytes + 511) & ~(size_t)511;
        return r;
    };
    int*   bh    = (int*)alloc((size_t)BH_TOT * 4);
    int*   sums  = (int*)alloc(1024 * 4);
    int*   off0  = (int*)alloc((size_t)(N_DST0 + 1) * 4);
    int*   off1  = (int*)alloc((size_t)(N_DST1 + 1) * 4);
    float* cs1   = (float*)alloc((size_t)N_DST0 * 4);
    int*   esrc0 = (int*)alloc((size_t)E0 * 4);
    int*   esrc1 = (int*)alloc((size_t)E1 * 4);
    unsigned short* W0p = (unsigned short*)alloc((size_t)32768 * 2);
    unsigned short* W1p = (unsigned short*)alloc((size_t)16384 * 2);
    // staging tables: NOW live simultaneously with xs (fine_fused writes xs while
    // reading staging) -> separate region, no aliasing with big.
    uint32_t*       stgd0 = (uint32_t*)alloc((size_t)E0 * 4);
    unsigned short* stgs0 = (unsigned short*)alloc((size_t)E0 * 2);
    uint32_t*       stgd1 = (uint32_t*)alloc((size_t)E1 * 4);
    unsigned short* stgs1 = (unsigned short*)alloc((size_t)E1 * 2);
    // big region: xs (102.4MB) at offset 0 -- after agg0, y1b (12.8MB) reuses it;
    // aggb (25.6MB) lives at offset bigA throughout layer 0.
    size_t bigA = (size_t)N_SRC0 * 128 * 2;   // xs (f16), later y1b (f16)
    size_t bigB = (size_t)N_DST0 * 128 * 2;   // aggb (bf16)
    char* big = alloc(bigA + bigB);

    uint2*    xs   = (uint2*)big;
    __half*   y1b  = (__half*)big;              // reuses xs region after agg0
    uint32_t* aggb = (uint32_t*)(big + bigA);

    // --- CSR build: hist -> scan(2) -> scatter -> fine(+prescale+packw) ---
    hist_fused<<<NB0 + NB1, 256, (NK_D0 + NK_S0) * 4, stream>>>(
        src0, dst0, E0, src1, dst1, E1, bh);
    const int nsb = (BH_TOT + SCAN_TILE - 1) / SCAN_TILE;   // 263
    scan1_kernel<<<nsb, 256, 0, stream>>>(bh, bh, sums, BH_TOT);
    scan2_kernel<<<1, 256, 0, stream>>>(sums, nsb);
    scat_fused<<<NB0 + NB1, 256, (NK_D0 + NK_S0) * 4, stream>>>(
        src0, dst0, E0, src1, dst1, E1, bh, sums, stgd0, stgs0, stgd1, stgs1);
    fine_fused<<<NK_D0 + NK_S0 + NK_D1 + NK_S1 + 192, 256, 0, stream>>>(
        stgd0, stgs0, stgd1, stgs1, bh, sums, E0, E1,
        off0, esrc0, off1, esrc1,
        (const float4*)x, xs, cs1, W0, W1, W0p, W1p);

    // layer 0 aggregation
    agg0_kernel<<<N_DST0 / 4, 256, 0, stream>>>(
        (const uint32_t*)xs, esrc0, off0, aggb);

    // fused GEMM0 + GEMM-T (h tile stays in LDS; writes y1b into dead xs region)
    gemm01_mfma<<<N_DST0 / 32, 256, 0, stream>>>(
        (const short*)aggb, (const short*)W0p, b0, (const short*)W1p, cs1, y1b);

    // layer 1 aggregation
    agg1_kernel<<<(N_DST1 + 15) / 16, 256, 0, stream>>>(
        (const uint2*)y1b, esrc1, off1, b1, out, N_DST1);
}

// Round 11
// 384.707 us; speedup vs baseline: 1.0139x; 1.0139x over previous
//
#include <hip/hip_runtime.h>
#include <hip/hip_bf16.h>
#include <hip/hip_fp16.h>
#include <stdint.h>

#define N_SRC0 400000
#define N_DST0 100000
#define N_DST1 25000

// coarse-bucket geometry: 256-node buckets everywhere (shift = 8)
#define SH_D0 8
#define NK_D0 391      // ceil(100000/256)
#define SH_S0 8
#define NK_S0 1563     // ceil(400000/256)
#define SH_D1 8
#define NK_D1 98       // ceil(25000/256)
#define SH_S1 8
#define NK_S1 391      // ceil(100000/256)
#define NB0 512
#define NB1 128

// bh concatenated layout offsets (element indices; scan order == staging order)
#define BH_D0 0
#define BH_S0 (NK_D0 * NB0)                    // 200192
#define BH_D1 (BH_S0 + NK_S0 * NB0)            // 1000448
#define BH_S1 (BH_D1 + NK_D1 * NB1)            // 1012992
#define BH_TOT (BH_S1 + NK_S1 * NB1)           // 1063040

typedef __attribute__((ext_vector_type(8))) short short8;
typedef __attribute__((ext_vector_type(4))) float f32x4;

__device__ __forceinline__ unsigned short f2bf(float f) {
    __hip_bfloat16 h = __float2bfloat16(f);
    union { __hip_bfloat16 h; unsigned short u; } c;
    c.h = h;
    return c.u;
}
__device__ __forceinline__ uint32_t packbf2(float a, float b) {
    return (uint32_t)f2bf(a) | ((uint32_t)f2bf(b) << 16);
}
__device__ __forceinline__ __half2 u2h2(uint32_t u) {
    return __builtin_bit_cast(__half2, u);
}

// ============ pass 1: per-block coarse histograms (src & dst fused) ============
__device__ __forceinline__ void hist_body(
        const int* __restrict__ src, const int* __restrict__ dst, int n,
        int sshift, int snb, int dshift, int dnb, int NB, int blk,
        int* __restrict__ bhd, int* __restrict__ bhs, int* h) {
    for (int i = threadIdx.x; i < dnb + snb; i += 256) h[i] = 0;
    __syncthreads();
    const int per = (n + NB - 1) / NB;
    const int b = blk * per;
    const int e = min(b + per, n);
    for (int i = b + threadIdx.x; i < e; i += 256) {
        atomicAdd(&h[dst[i] >> dshift], 1);
        atomicAdd(&h[dnb + (src[i] >> sshift)], 1);
    }
    __syncthreads();
    for (int i = threadIdx.x; i < dnb; i += 256) bhd[(size_t)i * NB + blk] = h[i];
    for (int i = threadIdx.x; i < snb; i += 256) bhs[(size_t)i * NB + blk] = h[dnb + i];
}

__global__ __launch_bounds__(256) void hist_fused(
        const int* __restrict__ src0, const int* __restrict__ dst0, int E0,
        const int* __restrict__ src1, const int* __restrict__ dst1, int E1,
        int* __restrict__ bh) {
    extern __shared__ int h[];
    if (blockIdx.x < NB0)
        hist_body(src0, dst0, E0, SH_S0, NK_S0, SH_D0, NK_D0, NB0, blockIdx.x,
                  bh + BH_D0, bh + BH_S0, h);
    else
        hist_body(src1, dst1, E1, SH_S1, NK_S1, SH_D1, NK_D1, NB1, blockIdx.x - NB0,
                  bh + BH_D1, bh + BH_S1, h);
}

// ============ global exclusive scan over bh (block-local; sums folded later) ====
#define SCAN_ITEMS 8
#define SCAN_TILE 2048   // == 256 * SCAN_ITEMS; sums index = elem >> 11

__global__ __launch_bounds__(256) void scan1_kernel(
        const int* __restrict__ in, int* __restrict__ out,
        int* __restrict__ sums, int n) {
    __shared__ int lds[256];
    const int tid = threadIdx.x;
    const int base = blockIdx.x * SCAN_TILE + tid * SCAN_ITEMS;
    int v[SCAN_ITEMS];
    int run = 0;
    #pragma unroll
    for (int i = 0; i < SCAN_ITEMS; ++i) {
        int t = (base + i < n) ? in[base + i] : 0;
        v[i] = run;
        run += t;
    }
    lds[tid] = run;
    __syncthreads();
    int incl = run;
    for (int off = 1; off < 256; off <<= 1) {
        int u = (tid >= off) ? lds[tid - off] : 0;
        __syncthreads();
        incl += u;
        lds[tid] = incl;
        __syncthreads();
    }
    if (tid == 255) sums[blockIdx.x] = incl;
    int excl = incl - run;
    #pragma unroll
    for (int i = 0; i < SCAN_ITEMS; ++i)
        if (base + i < n) out[base + i] = excl + v[i];
}

__global__ __launch_bounds__(256) void scan2_kernel(int* __restrict__ sums, int nb) {
    __shared__ int lds[256];
    const int tid = threadIdx.x;
    const int base = tid * 4;
    int v[4];
    int run = 0;
    #pragma unroll
    for (int i = 0; i < 4; ++i) {
        int t = (base + i < nb) ? sums[base + i] : 0;
        v[i] = run;
        run += t;
    }
    lds[tid] = run;
    __syncthreads();
    int incl = run;
    for (int off = 1; off < 256; off <<= 1) {
        int u = (tid >= off) ? lds[tid - off] : 0;
        __syncthreads();
        incl += u;
        lds[tid] = incl;
        __syncthreads();
    }
    int excl = incl - run;
    #pragma unroll
    for (int i = 0; i < 4; ++i)
        if (base + i < nb) sums[base + i] = excl + v[i];
}

// ============ pass 2: scatter to bucket-major staging ============
// dst-keyed table (u32): (d_local << ksh) | s ; src-keyed table (u8): s & 255.
// cursors = bh[..] + sums[gidx>>11] - Ttable  (table-relative)
__device__ __forceinline__ void scat_body(
        const int* __restrict__ src, const int* __restrict__ dst, int n,
        int sshift, int snb, int dshift, int dnb, int NB, int blk, int ksh,
        const int* __restrict__ bhd, const int* __restrict__ bhs,
        const int* __restrict__ sums, int goffd, int goffs, int Td, int Ts,
        uint32_t* __restrict__ stg_d, uint8_t* __restrict__ stg_s, int* cur) {
    for (int i = threadIdx.x; i < dnb; i += 256) {
        int gi = goffd + i * NB + blk;
        cur[i] = bhd[(size_t)i * NB + blk] + sums[gi >> 11] - Td;
    }
    for (int i = threadIdx.x; i < snb; i += 256) {
        int gi = goffs + i * NB + blk;
        cur[dnb + i] = bhs[(size_t)i * NB + blk] + sums[gi >> 11] - Ts;
    }
    __syncthreads();
    const int per = (n + NB - 1) / NB;
    const int b = blk * per;
    const int e = min(b + per, n);
    const int dmask = (1 << dshift) - 1;
    for (int i = b + threadIdx.x; i < e; i += 256) {
        int s = src[i], d = dst[i];
        int pd = atomicAdd(&cur[d >> dshift], 1);
        stg_d[pd] = ((uint32_t)(d & dmask) << ksh) | (uint32_t)s;
        int ps = atomicAdd(&cur[dnb + (s >> sshift)], 1);
        stg_s[ps] = (uint8_t)(s & 255);
    }
}

__global__ __launch_bounds__(256) void scat_fused(
        const int* __restrict__ src0, const int* __restrict__ dst0, int E0,
        const int* __restrict__ src1, const int* __restrict__ dst1, int E1,
        const int* __restrict__ bh, const int* __restrict__ sums,
        uint32_t* __restrict__ stgd0, uint8_t* __restrict__ stgs0,
        uint32_t* __restrict__ stgd1, uint8_t* __restrict__ stgs1) {
    extern __shared__ int cur[];
    if (blockIdx.x < NB0)
        scat_body(src0, dst0, E0, SH_S0, NK_S0, SH_D0, NK_D0, NB0, blockIdx.x, 19,
                  bh + BH_D0, bh + BH_S0, sums, BH_D0, BH_S0, 0, E0,
                  stgd0, stgs0, cur);
    else
        scat_body(src1, dst1, E1, SH_S1, NK_S1, SH_D1, NK_D1, NB1, blockIdx.x - NB0, 17,
                  bh + BH_D1, bh + BH_S1, sums, BH_D1, BH_S1, 2 * E0, 2 * E0 + E1,
                  stgd1, stgs1, cur);
}

// ============ pass 3: per-bucket fine CSR / degree / packw (fused) ============
// bases are table-relative: base = bh[k*NB] + sums[(goff+k*NB)>>11] - T
__device__ __forceinline__ int fold_base(const int* bht, const int* sums,
                                         int goff, int NB, int T, int k) {
    int gi = goff + k * NB;
    return bht[(size_t)k * NB] + sums[gi >> 11] - T;
}

__device__ __forceinline__ void fine_csr_body(
        const uint32_t* __restrict__ stg, const int* __restrict__ bht,
        const int* __restrict__ sums, int goff, int T,
        int NB, int ksh, int nbins, int total, int nbkt, int k,
        int* __restrict__ off, int* __restrict__ esrc, int* fine, int* part) {
    const int fb = 256;
    const int base = fold_base(bht, sums, goff, NB, T, k);
    const int end = (k + 1 < nbkt) ? fold_base(bht, sums, goff, NB, T, k + 1) : total;
    const int gb = k << 8;
    const int t = threadIdx.x;
    const uint32_t mask = (1u << ksh) - 1;
    fine[t] = 0;
    __syncthreads();
    int i = base + t;
    for (; i + 768 < end; i += 1024) {
        uint32_t v0 = stg[i], v1 = stg[i + 256], v2 = stg[i + 512], v3 = stg[i + 768];
        atomicAdd(&fine[v0 >> ksh], 1);
        atomicAdd(&fine[v1 >> ksh], 1);
        atomicAdd(&fine[v2 >> ksh], 1);
        atomicAdd(&fine[v3 >> ksh], 1);
    }
    for (; i < end; i += 256)
        atomicAdd(&fine[stg[i] >> ksh], 1);
    __syncthreads();
    int a = fine[t];
    part[t] = a;
    __syncthreads();
    int incl = a;
    for (int o = 1; o < 256; o <<= 1) {
        int u = (t >= o) ? part[t - o] : 0;
        __syncthreads();
        incl += u;
        part[t] = incl;
        __syncthreads();
    }
    fine[t] = incl - a;   // exclusive
    __syncthreads();
    {
        int g = gb + t;
        if (g < nbins) off[g] = base + fine[t];
        if (k == nbkt - 1 && t == 0) off[nbins] = total;
    }
    __syncthreads();
    i = base + t;
    for (; i + 768 < end; i += 1024) {
        uint32_t v0 = stg[i], v1 = stg[i + 256], v2 = stg[i + 512], v3 = stg[i + 768];
        int p0 = atomicAdd(&fine[v0 >> ksh], 1);
        esrc[base + p0] = (int)(v0 & mask);
        int p1 = atomicAdd(&fine[v1 >> ksh], 1);
        esrc[base + p1] = (int)(v1 & mask);
        int p2 = atomicAdd(&fine[v2 >> ksh], 1);
        esrc[base + p2] = (int)(v2 & mask);
        int p3 = atomicAdd(&fine[v3 >> ksh], 1);
        esrc[base + p3] = (int)(v3 & mask);
    }
    for (; i < end; i += 256) {
        uint32_t v = stg[i];
        int p = atomicAdd(&fine[v >> ksh], 1);
        esrc[base + p] = (int)(v & mask);
    }
}

__device__ __forceinline__ void fine_deg_body(
        const uint8_t* __restrict__ stg, const int* __restrict__ bht,
        const int* __restrict__ sums, int goff, int T,
        int NB, int nbins, int total, int nbkt, int k,
        float* __restrict__ csf, int* fine) {
    const int base = fold_base(bht, sums, goff, NB, T, k);
    const int end = (k + 1 < nbkt) ? fold_base(bht, sums, goff, NB, T, k + 1) : total;
    const int gb = k << 8;
    const int t = threadIdx.x;
    fine[t] = 0;
    __syncthreads();
    int i = base + t;
    for (; i + 768 < end; i += 1024) {
        uint32_t v0 = stg[i], v1 = stg[i + 256], v2 = stg[i + 512], v3 = stg[i + 768];
        atomicAdd(&fine[v0], 1);
        atomicAdd(&fine[v1], 1);
        atomicAdd(&fine[v2], 1);
        atomicAdd(&fine[v3], 1);
    }
    for (; i < end; i += 256)
        atomicAdd(&fine[stg[i]], 1);
    __syncthreads();
    int g = gb + t;
    if (g < nbins) {
        int c = fine[t];
        csf[g] = c > 0 ? rsqrtf((float)c) : 0.f;
    }
}

__global__ __launch_bounds__(256) void fine_fused(
        const uint32_t* __restrict__ stgd0, const uint8_t* __restrict__ stgs0,
        const uint32_t* __restrict__ stgd1, const uint8_t* __restrict__ stgs1,
        const int* __restrict__ bh, const int* __restrict__ sums,
        int E0, int E1,
        int* __restrict__ off0, int* __restrict__ esrc0,
        int* __restrict__ off1, int* __restrict__ esrc1,
        float* __restrict__ cs0, float* __restrict__ cs1,
        const float* __restrict__ W0, const float* __restrict__ W1,
        unsigned short* __restrict__ W0p, unsigned short* __restrict__ W1p) {
    __shared__ int fine[256];
    __shared__ int part[256];
    int kb = blockIdx.x;
    if (kb < NK_D0) {
        fine_csr_body(stgd0, bh + BH_D0, sums, BH_D0, 0,
                      NB0, 19, N_DST0, E0, NK_D0, kb, off0, esrc0, fine, part);
        return;
    }
    kb -= NK_D0;
    if (kb < NK_S0) {
        fine_deg_body(stgs0, bh + BH_S0, sums, BH_S0, E0,
                      NB0, N_SRC0, E0, NK_S0, kb, cs0, fine);
        return;
    }
    kb -= NK_S0;
    if (kb < NK_D1) {
        fine_csr_body(stgd1, bh + BH_D1, sums, BH_D1, 2 * E0,
                      NB1, 17, N_DST1, E1, NK_D1, kb, off1, esrc1, fine, part);
        return;
    }
    kb -= NK_D1;
    if (kb < NK_S1) {
        fine_deg_body(stgs1, bh + BH_S1, sums, BH_S1, 2 * E0 + E1,
                      NB1, N_DST0, E1, NK_S1, kb, cs1, fine);
        return;
    }
    kb -= NK_S1;
    // weight packs (independent of sort data)
    if (kb < 128) {
        int id = kb * 256 + threadIdx.x;
        int kk = id & 31, n2 = (id >> 5) & 255, kt = id >> 13;
        W0p[id] = f2bf(W0[(kt * 32 + kk) * 256 + n2]);
    } else {
        int id = (kb - 128) * 256 + threadIdx.x;
        int kk = id & 31, n2 = (id >> 5) & 63, kt = id >> 11;
        W1p[id] = f2bf(W1[(kt * 32 + kk) * 64 + n2]);
    }
}

// ---------------- prescale: xs = f16(x * cs0), [N_SRC0,128] ----------------
__global__ __launch_bounds__(256) void prescale_kernel(
        const float4* __restrict__ x4, const float* __restrict__ cs,
        uint2* __restrict__ xs) {
    int id = blockIdx.x * 256 + threadIdx.x;
    int row = id >> 5;   // 32 float4 per row
    float c = cs[row];
    float4 v = x4[id];
    uint2 o;
    o.x = __builtin_bit_cast(uint32_t, __floats2half2_rn(v.x * c, v.y * c));
    o.y = __builtin_bit_cast(uint32_t, __floats2half2_rn(v.z * c, v.w * c));
    xs[id] = o;
}

// ---------------- layer-0 aggregation: 64 lanes/row, u32 f16 gather, pk_add ----
__global__ __launch_bounds__(256) void agg0_kernel(
        const uint32_t* __restrict__ xs, const int* __restrict__ esrc,
        const int* __restrict__ off, uint32_t* __restrict__ aggb) {
    const int row = blockIdx.x * 4 + (threadIdx.x >> 6);
    const uint32_t t = threadIdx.x & 63;
    const int b = off[row], e = off[row + 1];
    const __half2 z = __builtin_bit_cast(__half2, 0u);
    __half2 a[16];
    #pragma unroll
    for (int k = 0; k < 16; ++k) a[k] = z;
    int i = b;
    for (; i + 15 < e; i += 16) {
        uint32_t idx[16];
        #pragma unroll
        for (int k = 0; k < 16; ++k)
            idx[k] = ((uint32_t)esrc[i + k] << 6) + t;
        #pragma unroll
        for (int k = 0; k < 16; ++k)
            a[k] = __hadd2(a[k], u2h2(xs[idx[k]]));
    }
    for (; i + 3 < e; i += 4) {
        #pragma unroll
        for (int k = 0; k < 4; ++k)
            a[k] = __hadd2(a[k], u2h2(xs[((uint32_t)esrc[i + k] << 6) + t]));
    }
    for (; i < e; ++i)
        a[0] = __hadd2(a[0], u2h2(xs[((uint32_t)esrc[i] << 6) + t]));
    #pragma unroll
    for (int k = 0; k < 8; ++k) a[k] = __hadd2(a[k], a[k + 8]);
    #pragma unroll
    for (int k = 0; k < 4; ++k) a[k] = __hadd2(a[k], a[k + 4]);
    __half2 s = __hadd2(__hadd2(a[0], a[1]), __hadd2(a[2], a[3]));
    float cd = (e > b) ? rsqrtf((float)(e - b)) : 0.f;
    aggb[(size_t)row * 64 + t] = packbf2(__low2float(s) * cd, __high2float(s) * cd);
}

// ---------------- fused GEMM: h = relu(agg@W0+b0) in LDS; y = (h@W1)*cs1 ----
__global__ __launch_bounds__(256) void gemm01_mfma(
        const short* __restrict__ A,            // aggb [N_DST0][128] bf16
        const short* __restrict__ B0p,          // [4][256][32] bf16
        const float* __restrict__ bias0,        // [256]
        const short* __restrict__ B1p,          // [8][64][32] bf16
        const float* __restrict__ cs1,          // [N_DST0]
        __half* __restrict__ Y) {               // [N_DST0][64] f16
    __shared__ short hs[32][264];               // row stride 528B: 2-way bank alias (free)
    const int w = threadIdx.x >> 6;
    const int l = threadIdx.x & 63;
    const int rbase = blockIdx.x * 32;
    const int lr = l & 15;
    const int lk = (l >> 4) * 8;
    const int orow0 = (l >> 4) * 4;

    // ---- phase A: h tile ----
    {
        const int cbase = w * 64;
        f32x4 acc[2][4] = {};
        #pragma unroll
        for (int kt = 0; kt < 4; ++kt) {
            short8 a[2], b[4];
            #pragma unroll
            for (int rt = 0; rt < 2; ++rt)
                a[rt] = *(const short8*)(A + (size_t)(rbase + rt * 16 + lr) * 128 + kt * 32 + lk);
            #pragma unroll
            for (int ct = 0; ct < 4; ++ct)
                b[ct] = *(const short8*)(B0p + (size_t)(kt * 256 + cbase + ct * 16 + lr) * 32 + lk);
            #pragma unroll
            for (int rt = 0; rt < 2; ++rt)
                #pragma unroll
                for (int ct = 0; ct < 4; ++ct)
                    acc[rt][ct] = __builtin_amdgcn_mfma_f32_16x16x32_bf16(a[rt], b[ct], acc[rt][ct], 0, 0, 0);
        }
        #pragma unroll
        for (int rt = 0; rt < 2; ++rt) {
            #pragma unroll
            for (int ct = 0; ct < 4; ++ct) {
                int col = cbase + ct * 16 + lr;
                float bv = bias0[col];
                #pragma unroll
                for (int j = 0; j < 4; ++j)
                    hs[rt * 16 + orow0 + j][col] = (short)f2bf(fmaxf(acc[rt][ct][j] + bv, 0.f));
            }
        }
    }
    __syncthreads();

    // ---- phase B: y tile, wave w covers cols [w*16, w*16+16), K = 256 ----
    {
        f32x4 acc2[2] = {};
        #pragma unroll
        for (int kt = 0; kt < 8; ++kt) {
            short8 b1 = *(const short8*)(B1p + (size_t)(kt * 64 + w * 16 + lr) * 32 + lk);
            #pragma unroll
            for (int rt = 0; rt < 2; ++rt) {
                short8 av = *(const short8*)(&hs[rt * 16 + lr][kt * 32 + lk]);
                acc2[rt] = __builtin_amdgcn_mfma_f32_16x16x32_bf16(av, b1, acc2[rt], 0, 0, 0);
            }
        }
        #pragma unroll
        for (int rt = 0; rt < 2; ++rt) {
            #pragma unroll
            for (int j = 0; j < 4; ++j) {
                int row = rbase + rt * 16 + orow0 + j;
                float c = cs1[row];
                Y[(size_t)row * 64 + w * 16 + lr] = __float2half(acc2[rt][j] * c);
            }
        }
    }
}

// ---------------- layer-1 aggregation: 16 lanes/row, uint2 f16 gather ------
__global__ __launch_bounds__(256) void agg1_kernel(
        const uint2* __restrict__ y2, const int* __restrict__ esrc,
        const int* __restrict__ off, const float* __restrict__ bias,
        float* __restrict__ out, int nrows) {
    int row = blockIdx.x * 16 + (threadIdx.x >> 4);
    int t = threadIdx.x & 15;
    if (row >= nrows) return;
    int b = off[row], e = off[row + 1];
    const __half2 z = __builtin_bit_cast(__half2, 0u);
    __half2 aA0 = z, aA1 = z, aB0 = z, aB1 = z;
    int i = b;
    for (; i + 8 <= e; i += 8) {
        #pragma unroll
        for (int k = 0; k < 8; k += 2) {
            int s0 = esrc[i + k], s1 = esrc[i + k + 1];
            uint2 v0 = y2[(size_t)s0 * 16 + t];
            uint2 v1 = y2[(size_t)s1 * 16 + t];
            aA0 = __hadd2(aA0, u2h2(v0.x));
            aA1 = __hadd2(aA1, u2h2(v0.y));
            aB0 = __hadd2(aB0, u2h2(v1.x));
            aB1 = __hadd2(aB1, u2h2(v1.y));
        }
    }
    for (; i < e; ++i) {
        uint2 v = y2[(size_t)esrc[i] * 16 + t];
        aA0 = __hadd2(aA0, u2h2(v.x));
        aA1 = __hadd2(aA1, u2h2(v.y));
    }
    float cd = (e > b) ? rsqrtf((float)(e - b)) : 0.f;
    __half2 s0 = __hadd2(aA0, aB0), s1 = __hadd2(aA1, aB1);
    float4 bv = *(const float4*)(bias + t * 4);
    float4 o;
    o.x = fmaxf(__low2float(s0) * cd + bv.x, 0.f);
    o.y = fmaxf(__high2float(s0) * cd + bv.y, 0.f);
    o.z = fmaxf(__low2float(s1) * cd + bv.z, 0.f);
    o.w = fmaxf(__high2float(s1) * cd + bv.w, 0.f);
    *(float4*)(out + (size_t)row * 64 + t * 4) = o;
}

extern "C" void kernel_launch(void* const* d_in, const int* in_sizes, int n_in,
                              void* d_out, int out_size, void* d_ws, size_t ws_size,
                              hipStream_t stream) {
    const float* x    = (const float*)d_in[0];
    const int*   src0 = (const int*)d_in[1];
    const int*   dst0 = (const int*)d_in[2];
    const int*   src1 = (const int*)d_in[3];
    const int*   dst1 = (const int*)d_in[4];
    const float* W0   = (const float*)d_in[5];
    const float* b0   = (const float*)d_in[6];
    const float* W1   = (const float*)d_in[7];
    const float* b1   = (const float*)d_in[8];
    float* out = (float*)d_out;

    const int E0 = in_sizes[1];
    const int E1 = in_sizes[3];

    char* p = (char*)d_ws;
    auto alloc = [&](size_t bytes) {
        char* r = p;
        p += (bytes + 511) & ~(size_t)511;
        return r;
    };
    int*   bh    = (int*)alloc((size_t)BH_TOT * 4);
    int*   sums  = (int*)alloc(1024 * 4);
    int*   off0  = (int*)alloc((size_t)(N_DST0 + 1) * 4);
    int*   off1  = (int*)alloc((size_t)(N_DST1 + 1) * 4);
    float* cs0   = (float*)alloc((size_t)N_SRC0 * 4);
    float* cs1   = (float*)alloc((size_t)N_DST0 * 4);
    int*   esrc0 = (int*)alloc((size_t)E0 * 4);
    int*   esrc1 = (int*)alloc((size_t)E1 * 4);
    unsigned short* W0p = (unsigned short*)alloc((size_t)32768 * 2);
    unsigned short* W1p = (unsigned short*)alloc((size_t)16384 * 2);
    // big region: staging tables (~20MB, dead before prescale);
    // then xs (102.4MB) at offset 0 -- after agg0, y1b (12.8MB) reuses offset 0;
    // aggb (25.6MB) lives at offset bigA throughout layer 0.
    size_t bigA = (size_t)N_SRC0 * 128 * 2;   // xs (f16), later y1b (f16)
    size_t bigB = (size_t)N_DST0 * 128 * 2;   // aggb (bf16)
    char* big = alloc(bigA + bigB);

    // staging carve inside big (dead before prescale writes xs)
    char* q = big;
    auto carve = [&](size_t bytes) {
        char* r = q;
        q += (bytes + 511) & ~(size_t)511;
        return r;
    };
    uint32_t* stgd0 = (uint32_t*)carve((size_t)E0 * 4);
    uint8_t*  stgs0 = (uint8_t*)carve((size_t)E0);
    uint32_t* stgd1 = (uint32_t*)carve((size_t)E1 * 4);
    uint8_t*  stgs1 = (uint8_t*)carve((size_t)E1);

    uint2*    xs   = (uint2*)big;
    __half*   y1b  = (__half*)big;              // reuses xs region after agg0
    uint32_t* aggb = (uint32_t*)(big + bigA);

    // --- CSR build: hist -> scan(2) -> scatter -> fine(+packw) ---
    hist_fused<<<NB0 + NB1, 256, (NK_D0 + NK_S0) * 4, stream>>>(
        src0, dst0, E0, src1, dst1, E1, bh);
    const int nsb = (BH_TOT + SCAN_TILE - 1) / SCAN_TILE;   // 520
    scan1_kernel<<<nsb, 256, 0, stream>>>(bh, bh, sums, BH_TOT);
    scan2_kernel<<<1, 256, 0, stream>>>(sums, nsb);
    scat_fused<<<NB0 + NB1, 256, (NK_D0 + NK_S0) * 4, stream>>>(
        src0, dst0, E0, src1, dst1, E1, bh, sums, stgd0, stgs0, stgd1, stgs1);
    fine_fused<<<NK_D0 + NK_S0 + NK_D1 + NK_S1 + 192, 256, 0, stream>>>(
        stgd0, stgs0, stgd1, stgs1, bh, sums, E0, E1,
        off0, esrc0, off1, esrc1, cs0, cs1, W0, W1, W0p, W1p);

    // --- prescale x -> f16 (staging fully consumed; big region repurposed) ---
    prescale_kernel<<<N_SRC0 * 32 / 256, 256, 0, stream>>>((const float4*)x, cs0, xs);

    // layer 0 aggregation
    agg0_kernel<<<N_DST0 / 4, 256, 0, stream>>>(
        (const uint32_t*)xs, esrc0, off0, aggb);

    // fused GEMM0 + GEMM-T (h tile stays in LDS; writes y1b into dead xs region)
    gemm01_mfma<<<N_DST0 / 32, 256, 0, stream>>>(
        (const short*)aggb, (const short*)W0p, b0, (const short*)W1p, cs1, y1b);

    // layer 1 aggregation
    agg1_kernel<<<(N_DST1 + 15) / 16, 256, 0, stream>>>(
        (const uint2*)y1b, esrc1, off1, b1, out, N_DST1);
}